// Round 17
// baseline (44.122 us; speedup 1.0000x reference)
//
#include <hip/hip_runtime.h>
#include <hip/hip_bf16.h>

// RetrieverBase: q[64][32][128] f32, p[128][180][128] f32
// out = concat(term_relevance[64][128][32][180], query_maxsim[64][128][32], relevance[64][128])
#define A_N 64
#define B_N 128
#define Q_N 32
#define D_N 180
#define V_N 128

typedef __attribute__((ext_vector_type(8))) short bf16x8;   // 8 bf16 (4 VGPRs)
typedef __attribute__((ext_vector_type(4))) float f32x4;

__device__ __forceinline__ short f2bf(float f) {
  __hip_bfloat16 h = __float2bfloat16(f);
  return (short)__builtin_bit_cast(unsigned short, h);
}

__device__ __forceinline__ bf16x8 pack8(const f32x4& lo, const f32x4& hi) {
  bf16x8 v;
  v[0] = f2bf(lo[0]); v[1] = f2bf(lo[1]); v[2] = f2bf(lo[2]); v[3] = f2bf(lo[3]);
  v[4] = f2bf(hi[0]); v[5] = f2bf(hi[1]); v[6] = f2bf(hi[2]); v[7] = f2bf(hi[3]);
  return v;
}

// Per-wave LDS fence (R11-R14 proven): drains this wave's DS queue for the
// cross-lane ds_write -> ds_read handoff. lgkm-only: global stores keep
// draining in the background. NOT a block barrier.
__device__ __forceinline__ void lds_fence() {
  asm volatile("s_waitcnt lgkmcnt(0)" ::: "memory");
  __builtin_amdgcn_sched_barrier(0);
}

// R17 = R14 champion (43.0us) + deferred-qt1 store interleave.
// R15/R16 de-bundle verdict: nt = -4.3us (bypasses the L2 write-combining
// our 16B-lane stores rely on), staging unroll = neutral. R14 restored.
// Remaining gap vs the ~33-36us floor: store-issue DUTY CYCLE -- stores
// issued in 2x12 bursts per job; during each ~3us compute phase the CU
// store buffer drains empty (~2us idle write pipe per job). Fix with NO
// structural change: defer each job's qt1 store burst into the NEXT job's
// compute loop (1 cbuf chunk read + 1KB store per dt, 12 dt = 12 chunks).
// cbuf stays single-buffered: compute of job j only READS job j-1's qt1;
// post-loop lgkm fence = WAR protection before qt0 assembly rewrites it.
// Tail: job 3's qt1 stored in a short epilogue.
// Kept from R14: grid 256 = 2 ag x 128 b (b fast: bid%8==b%8 pins each
// XCD's p slice in L2), block 512 = 8 waves, 1 block/CU, p staged once to
// XOR-swizzled LDS, ONE block barrier, 4 pipelined jobs/wave with double-
// buffered q-fragments, all 24 accs live, full-row cbuf (11.25KB contiguous
// per q-half = 180 full 64B lines, L2 write-combined), in-register
// maxsim/relevance. LDS: plds 46080 + cbuf 8x11520 = 138240 B.
__global__ __launch_bounds__(512, 2) void score_kernel(
    const float* __restrict__ q, const float* __restrict__ p,
    float* __restrict__ out) {
  const int bid  = blockIdx.x;
  const int b    = bid & (B_N - 1);
  const int ag   = bid >> 7;          // 0..1
  const int tid  = threadIdx.x;
  const int wv   = tid >> 6;          // 0..7
  const int lane = tid & 63;
  const int l16  = lane & 15;
  const int g    = lane >> 4;         // 0..3

  const float* __restrict__ pb = p + (size_t)b * D_N * V_N;

  // ---- stage p[b] -> LDS bf16, swizzled: 2880 16B-chunks over 512 threads ----
  __shared__ ushort plds[D_N * V_N];                    // 46080 B
  __shared__ __align__(16) float cbuf[8][16 * D_N];     // 8 x 11520 B
  for (int c = tid; c < D_N * (V_N / 8); c += 512) {
    const int r  = c >> 4;
    const int s  = c & 15;
    const int sp = (s & 8) | ((s & 7) ^ (r & 7));
    const float* src = pb + (size_t)r * V_N + s * 8;
    *reinterpret_cast<bf16x8*>(&plds[r * V_N + sp * 8]) =
        pack8(*reinterpret_cast<const f32x4*>(src),
              *reinterpret_cast<const f32x4*>(src + 4));
  }

  // q B-fragments, double-buffered across jobs: load job 0 now.
  // B[k][col=q]; lane reads q[qt*16+l16][kk*32+g*8 ..+7]
  bf16x8 qf[2][2][4];   // [buf][qt][kk]
#define LOADQF(buf, jj)                                                       \
  {                                                                           \
    const int aq = ag * 32 + (jj) * 8 + wv;                                   \
    const float* __restrict__ qa = q + (size_t)aq * Q_N * V_N;                \
    _Pragma("unroll")                                                         \
    for (int qt = 0; qt < 2; ++qt)                                            \
      _Pragma("unroll")                                                       \
      for (int kk = 0; kk < 4; ++kk) {                                        \
        const float* s = qa + (size_t)(qt * 16 + l16) * V_N + kk * 32 + g * 8;\
        qf[buf][qt][kk] = pack8(*reinterpret_cast<const f32x4*>(s),          \
                                *reinterpret_cast<const f32x4*>(s + 4));     \
      }                                                                       \
  }
  LOADQF(0, 0);

  __syncthreads();   // staging complete — the ONLY block barrier

  float* cw = cbuf[wv];
  const size_t TERM_SZ = (size_t)A_N * B_N * Q_N * D_N;
  const size_t MS_SZ   = (size_t)A_N * B_N * Q_N;

#pragma unroll
  for (int j = 0; j < 4; ++j) {   // fully unrolled: all indices compile-time
    const int a  = ag * 32 + j * 8 + wv;
    const int jb = j & 1;         // qf buffer for this job (compile-time)
    // prev job's qt1 output base (cbuf still holds it; valid for j>0)
    const size_t outb_prev = (j > 0)
        ? ((size_t)(ag * 32 + (j - 1) * 8 + wv) * B_N + b) * (size_t)(Q_N * D_N)
          + (size_t)16 * D_N
        : 0;

    // ---- compute: all 12 d-tiles, both q-halves; pf read once per dt.
    // Interleaved: chunk dt of prev job's qt1 streamed from cbuf -> HBM,
    // keeping the store pipe fed through the compute phase. ----
    f32x4 acc[2][12];
#pragma unroll
    for (int qt = 0; qt < 2; ++qt)
#pragma unroll
      for (int dt = 0; dt < 12; ++dt)
        acc[qt][dt] = (f32x4){0.f, 0.f, 0.f, 0.f};

#pragma unroll
    for (int dt = 0; dt < 12; ++dt) {
      const int drow = dt * 16 + l16;
      const int dr   = drow < D_N ? drow : (D_N - 1);  // tail clamp, max-safe

      bf16x8 pf[4];
#pragma unroll
      for (int kk = 0; kk < 4; ++kk) {
        const int s  = kk * 4 + g;
        const int sp = (s & 8) | ((s & 7) ^ (dr & 7));
        pf[kk] = *reinterpret_cast<const bf16x8*>(&plds[dr * V_N + sp * 8]);
      }
#pragma unroll
      for (int kk = 0; kk < 4; ++kk) {
        acc[0][dt] = __builtin_amdgcn_mfma_f32_16x16x32_bf16(pf[kk], qf[jb][0][kk], acc[0][dt], 0, 0, 0);
        acc[1][dt] = __builtin_amdgcn_mfma_f32_16x16x32_bf16(pf[kk], qf[jb][1][kk], acc[1][dt], 0, 0, 0);
      }

      if (j > 0) {   // deferred store: prev job qt1, chunk dt (12 chunks total)
        const int off = dt * 256 + lane * 4;
        if (dt < 11 || lane < 16) {
          f32x4 v = *reinterpret_cast<const f32x4*>(&cw[off]);
          *reinterpret_cast<f32x4*>(out + outb_prev + off) = v;
        }
      }
    }
    if (j > 0) lds_fence();   // WAR: prev qt1 cbuf reads done before rewrite

    // prefetch next job's q-fragments (completes under this job's stores)
    if (j < 3) LOADQF(!jb ? 1 : 0, j + 1);

    // per-lane maxsim over owned d (clamped dups are max-safe)
    float qm[2] = {-INFINITY, -INFINITY};
#pragma unroll
    for (int qt = 0; qt < 2; ++qt)
#pragma unroll
      for (int dt = 0; dt < 12; ++dt)
        qm[qt] = fmaxf(qm[qt], fmaxf(fmaxf(acc[qt][dt][0], acc[qt][dt][1]),
                                     fmaxf(acc[qt][dt][2], acc[qt][dt][3])));

    const size_t outb = ((size_t)a * B_N + b) * (size_t)(Q_N * D_N);

    // ---- qt0: assemble 16 full 720B rows in cbuf, burst-store linearly ----
#pragma unroll
    for (int dt = 0; dt < 12; ++dt) {
      if (dt < 11 || g == 0)   // dt==11: only d 176..179 (g==0) valid
        *reinterpret_cast<f32x4*>(&cw[l16 * D_N + dt * 16 + g * 4]) = acc[0][dt];
    }
    lds_fence();   // cross-lane: row writes visible before linear reads
#pragma unroll
    for (int c = 0; c < 12; ++c) {       // 11 x 1KB + 1 x 256B (lanes<16)
      const int off = c * 256 + lane * 4;
      if (c < 11 || lane < 16) {
        f32x4 v = *reinterpret_cast<const f32x4*>(&cw[off]);
        *reinterpret_cast<f32x4*>(out + outb + off) = v;
      }
    }
    lds_fence();   // WAR: qt0 reads landed before qt1 assembly rewrites cbuf

    // ---- qt1: assemble only; stores deferred into next job's compute ----
#pragma unroll
    for (int dt = 0; dt < 12; ++dt) {
      if (dt < 11 || g == 0)
        *reinterpret_cast<f32x4*>(&cw[l16 * D_N + dt * 16 + g * 4]) = acc[1][dt];
    }
    lds_fence();   // writes visible before next job's interleaved reads

    // max across the 4 g-groups (different d sub-rows, same q)
    float qm0 = qm[0], qm1 = qm[1];
    qm0 = fmaxf(qm0, __shfl_xor(qm0, 16, 64));
    qm0 = fmaxf(qm0, __shfl_xor(qm0, 32, 64));
    qm1 = fmaxf(qm1, __shfl_xor(qm1, 16, 64));
    qm1 = fmaxf(qm1, __shfl_xor(qm1, 32, 64));

    if (lane < 16) {   // maxsim for q = qt*16 + lane
      float* ms = out + TERM_SZ + ((size_t)a * B_N + b) * Q_N;
      ms[lane]      = qm0;
      ms[16 + lane] = qm1;
    }

    // relevance = sum over 32 q of maxsim (qm replicated across g-groups)
    float s = qm0 + qm1;
    s += __shfl_xor(s, 1, 64);
    s += __shfl_xor(s, 2, 64);
    s += __shfl_xor(s, 4, 64);
    s += __shfl_xor(s, 8, 64);
    if (lane == 0)
      out[TERM_SZ + MS_SZ + (size_t)a * B_N + b] = s;
  }
#undef LOADQF

  // ---- epilogue: job 3's qt1 (still in cbuf) ----
  {
    const int a3 = ag * 32 + 3 * 8 + wv;
    const size_t outb3 = ((size_t)a3 * B_N + b) * (size_t)(Q_N * D_N)
                         + (size_t)16 * D_N;
#pragma unroll
    for (int c = 0; c < 12; ++c) {
      const int off = c * 256 + lane * 4;
      if (c < 11 || lane < 16) {
        f32x4 v = *reinterpret_cast<const f32x4*>(&cw[off]);
        *reinterpret_cast<f32x4*>(out + outb3 + off) = v;
      }
    }
  }
}

extern "C" void kernel_launch(void* const* d_in, const int* in_sizes, int n_in,
                              void* d_out, int out_size, void* d_ws, size_t ws_size,
                              hipStream_t stream) {
  const float* q = (const float*)d_in[0];
  const float* p = (const float*)d_in[1];
  float* out = (float*)d_out;
  dim3 grid(256);    // 2 a-groups x 128 b: exactly one block per CU
  dim3 block(512);   // 8 waves; 4 pipelined (a,b) jobs per wave
  hipLaunchKernelGGL(score_kernel, grid, block, 0, stream, q, p, out);
}

// Round 18
// 43.035 us; speedup vs baseline: 1.0253x; 1.0253x over previous
//
#include <hip/hip_runtime.h>
#include <hip/hip_bf16.h>

// RetrieverBase: q[64][32][128] f32, p[128][180][128] f32
// out = concat(term_relevance[64][128][32][180], query_maxsim[64][128][32], relevance[64][128])
//
// FINAL (champion, R14 = 42.97us): the series plateaued at 43us across three
// independent store-scheduling structures (R14 burst / R16 +unrolled stage /
// R17 interleaved-deferred) -> empirical mixed-stream ceiling: ~215MB HBM
// traffic (190 write + 25 fetch) at ~5.0 TB/s effective. Key mechanisms
// learned: (1) stores must form full 64B lines via LDS-assembled linear
// bursts (L2 write-combining; partial 16B@720B-stride caps at ~2-3.5 TB/s,
// R1-R7); (2) nontemporal kills the write-combining (-10%, R15); (3) one
// job per wave per step + full-line stores avoids a 4x partial-line RMW
// blowup (R4/R9); (4) p staged once per CU in XOR-swizzled LDS removes all
// global-load stall chains; (5) zero block barriers in the hot path.
#define A_N 64
#define B_N 128
#define Q_N 32
#define D_N 180
#define V_N 128

typedef __attribute__((ext_vector_type(8))) short bf16x8;   // 8 bf16 (4 VGPRs)
typedef __attribute__((ext_vector_type(4))) float f32x4;

__device__ __forceinline__ short f2bf(float f) {
  __hip_bfloat16 h = __float2bfloat16(f);
  return (short)__builtin_bit_cast(unsigned short, h);
}

__device__ __forceinline__ bf16x8 pack8(const f32x4& lo, const f32x4& hi) {
  bf16x8 v;
  v[0] = f2bf(lo[0]); v[1] = f2bf(lo[1]); v[2] = f2bf(lo[2]); v[3] = f2bf(lo[3]);
  v[4] = f2bf(hi[0]); v[5] = f2bf(hi[1]); v[6] = f2bf(hi[2]); v[7] = f2bf(hi[3]);
  return v;
}

// Per-wave LDS fence: drains this wave's DS queue for the cross-lane
// ds_write -> ds_read handoff. lgkm-only: global stores keep draining in
// the background. NOT a block barrier.
__device__ __forceinline__ void lds_fence() {
  asm volatile("s_waitcnt lgkmcnt(0)" ::: "memory");
  __builtin_amdgcn_sched_barrier(0);
}

__global__ __launch_bounds__(512, 2) void score_kernel(
    const float* __restrict__ q, const float* __restrict__ p,
    float* __restrict__ out) {
  const int bid  = blockIdx.x;
  const int b    = bid & (B_N - 1);
  const int ag   = bid >> 7;          // 0..1
  const int tid  = threadIdx.x;
  const int wv   = tid >> 6;          // 0..7
  const int lane = tid & 63;
  const int l16  = lane & 15;
  const int g    = lane >> 4;         // 0..3

  const float* __restrict__ pb = p + (size_t)b * D_N * V_N;

  // ---- stage p[b] -> LDS bf16, swizzled: 2880 16B-chunks over 512 threads ----
  __shared__ ushort plds[D_N * V_N];                    // 46080 B
  __shared__ __align__(16) float cbuf[8][16 * D_N];     // 8 x 11520 B
  for (int c = tid; c < D_N * (V_N / 8); c += 512) {
    const int r  = c >> 4;
    const int s  = c & 15;
    const int sp = (s & 8) | ((s & 7) ^ (r & 7));
    const float* src = pb + (size_t)r * V_N + s * 8;
    *reinterpret_cast<bf16x8*>(&plds[r * V_N + sp * 8]) =
        pack8(*reinterpret_cast<const f32x4*>(src),
              *reinterpret_cast<const f32x4*>(src + 4));
  }

  // q B-fragments, double-buffered across jobs: load job 0 now.
  // B[k][col=q]; lane reads q[qt*16+l16][kk*32+g*8 ..+7]
  bf16x8 qf[2][2][4];   // [buf][qt][kk]
#define LOADQF(buf, jj)                                                       \
  {                                                                           \
    const int aq = ag * 32 + (jj) * 8 + wv;                                   \
    const float* __restrict__ qa = q + (size_t)aq * Q_N * V_N;                \
    _Pragma("unroll")                                                         \
    for (int qt = 0; qt < 2; ++qt)                                            \
      _Pragma("unroll")                                                       \
      for (int kk = 0; kk < 4; ++kk) {                                        \
        const float* s = qa + (size_t)(qt * 16 + l16) * V_N + kk * 32 + g * 8;\
        qf[buf][qt][kk] = pack8(*reinterpret_cast<const f32x4*>(s),          \
                                *reinterpret_cast<const f32x4*>(s + 4));     \
      }                                                                       \
  }
  LOADQF(0, 0);

  __syncthreads();   // staging complete — the ONLY block barrier

  float* cw = cbuf[wv];
  const size_t TERM_SZ = (size_t)A_N * B_N * Q_N * D_N;
  const size_t MS_SZ   = (size_t)A_N * B_N * Q_N;

#pragma unroll
  for (int j = 0; j < 4; ++j) {   // fully unrolled: all indices compile-time
    const int a  = ag * 32 + j * 8 + wv;
    const int jb = j & 1;         // qf buffer for this job (compile-time)

    // ---- compute: all 12 d-tiles, both q-halves; pf read once per dt ----
    f32x4 acc[2][12];
#pragma unroll
    for (int qt = 0; qt < 2; ++qt)
#pragma unroll
      for (int dt = 0; dt < 12; ++dt)
        acc[qt][dt] = (f32x4){0.f, 0.f, 0.f, 0.f};

#pragma unroll
    for (int dt = 0; dt < 12; ++dt) {
      const int drow = dt * 16 + l16;
      const int dr   = drow < D_N ? drow : (D_N - 1);  // tail clamp, max-safe

      bf16x8 pf[4];
#pragma unroll
      for (int kk = 0; kk < 4; ++kk) {
        const int s  = kk * 4 + g;
        const int sp = (s & 8) | ((s & 7) ^ (dr & 7));
        pf[kk] = *reinterpret_cast<const bf16x8*>(&plds[dr * V_N + sp * 8]);
      }
#pragma unroll
      for (int kk = 0; kk < 4; ++kk) {
        acc[0][dt] = __builtin_amdgcn_mfma_f32_16x16x32_bf16(pf[kk], qf[jb][0][kk], acc[0][dt], 0, 0, 0);
        acc[1][dt] = __builtin_amdgcn_mfma_f32_16x16x32_bf16(pf[kk], qf[jb][1][kk], acc[1][dt], 0, 0, 0);
      }
    }

    // prefetch next job's q-fragments: global loads issue here and complete
    // under this job's store phase (compiler inserts the waitcnt at next use)
    if (j < 3) LOADQF(!jb ? 1 : 0, j + 1);

    // per-lane maxsim over owned d (clamped dups are max-safe)
    float qm[2] = {-INFINITY, -INFINITY};
#pragma unroll
    for (int qt = 0; qt < 2; ++qt)
#pragma unroll
      for (int dt = 0; dt < 12; ++dt)
        qm[qt] = fmaxf(qm[qt], fmaxf(fmaxf(acc[qt][dt][0], acc[qt][dt][1]),
                                     fmaxf(acc[qt][dt][2], acc[qt][dt][3])));

    // ---- store: per q-half, assemble 16 full 720B rows in cbuf, stream
    // linearly (11.25KB contiguous, 64B-aligned = 180 full lines) ----
    const size_t outb = ((size_t)a * B_N + b) * (size_t)(Q_N * D_N);
#pragma unroll
    for (int qt = 0; qt < 2; ++qt) {
#pragma unroll
      for (int dt = 0; dt < 12; ++dt) {
        if (dt < 11 || g == 0)   // dt==11: only d 176..179 (g==0) valid
          *reinterpret_cast<f32x4*>(&cw[l16 * D_N + dt * 16 + g * 4]) = acc[qt][dt];
      }
      lds_fence();   // cross-lane: row writes visible before linear reads

#pragma unroll
      for (int c = 0; c < 12; ++c) {       // 11 x 1KB + 1 x 256B (lanes<16)
        const int off = c * 256 + lane * 4;
        if (c < 11 || lane < 16) {
          f32x4 v = *reinterpret_cast<const f32x4*>(&cw[off]);
          *reinterpret_cast<f32x4*>(out + outb + (size_t)qt * 16 * D_N + off) = v;
        }
      }
      lds_fence();   // WAR: reads landed before cbuf is rewritten
    }

    // max across the 4 g-groups (different d sub-rows, same q)
    float qm0 = qm[0], qm1 = qm[1];
    qm0 = fmaxf(qm0, __shfl_xor(qm0, 16, 64));
    qm0 = fmaxf(qm0, __shfl_xor(qm0, 32, 64));
    qm1 = fmaxf(qm1, __shfl_xor(qm1, 16, 64));
    qm1 = fmaxf(qm1, __shfl_xor(qm1, 32, 64));

    if (lane < 16) {   // maxsim for q = qt*16 + lane
      float* ms = out + TERM_SZ + ((size_t)a * B_N + b) * Q_N;
      ms[lane]      = qm0;
      ms[16 + lane] = qm1;
    }

    // relevance = sum over 32 q of maxsim (qm replicated across g-groups)
    float s = qm0 + qm1;
    s += __shfl_xor(s, 1, 64);
    s += __shfl_xor(s, 2, 64);
    s += __shfl_xor(s, 4, 64);
    s += __shfl_xor(s, 8, 64);
    if (lane == 0)
      out[TERM_SZ + MS_SZ + (size_t)a * B_N + b] = s;
  }
#undef LOADQF
}

extern "C" void kernel_launch(void* const* d_in, const int* in_sizes, int n_in,
                              void* d_out, int out_size, void* d_ws, size_t ws_size,
                              hipStream_t stream) {
  const float* q = (const float*)d_in[0];
  const float* p = (const float*)d_in[1];
  float* out = (float*)d_out;
  dim3 grid(256);    // 2 a-groups x 128 b: exactly one block per CU
  dim3 block(512);   // 8 waves; 4 pipelined (a,b) jobs per wave
  hipLaunchKernelGGL(score_kernel, grid, block, 0, stream, q, p, out);
}